// Round 11
// baseline (444.433 us; speedup 1.0000x reference)
//
#include <hip/hip_runtime.h>
#include <hip/hip_bf16.h>

#define BATCH 4
#define S_LEN 2048
#define D_DIM 1024
#define NHEAD 16
#define HDIM 64

// Q pre-scale: 1/sqrt(HDIM) * log2(e), so softmax works in exp2 domain.
#define QSCALE 0.18033688011112042f

typedef __attribute__((ext_vector_type(8))) __bf16 bf16x8;
typedef __attribute__((ext_vector_type(4))) __bf16 bf16x4;
typedef __attribute__((ext_vector_type(4))) float f32x4;

static __device__ inline unsigned int bf16_bits(float f) {
    __bf16 h = (__bf16)f;
    return (unsigned int)__builtin_bit_cast(unsigned short, h);
}

// ---------------------------------------------------------------------------
// fp32 -> bf16 bulk convert, 8 elems/thread, 16B stores.
// ---------------------------------------------------------------------------
__global__ __launch_bounds__(256) void cvt_kernel(
    const float* __restrict__ src, __bf16* __restrict__ dst, int n8)
{
    int i = blockIdx.x * 256 + threadIdx.x;
    if (i >= n8) return;
    const f32x4* p = reinterpret_cast<const f32x4*>(src + (size_t)i * 8);
    f32x4 a = p[0], b = p[1];
    bf16x8 r;
    r[0] = (__bf16)a[0]; r[1] = (__bf16)a[1]; r[2] = (__bf16)a[2]; r[3] = (__bf16)a[3];
    r[4] = (__bf16)b[0]; r[5] = (__bf16)b[1]; r[6] = (__bf16)b[2]; r[7] = (__bf16)b[3];
    *reinterpret_cast<bf16x8*>(dst + (size_t)i * 8) = r;
}

// ---------------------------------------------------------------------------
// Projection GEMM (m97-style): C[m][n] = sum_d xb[m][d] * wb[n][d]
// q output is pre-scaled by QSCALE. q,k -> [bh][s][e]; v -> [bh][e][s].
// ---------------------------------------------------------------------------
__global__ __launch_bounds__(256) void proj_gemm_kernel(
    const __bf16* __restrict__ xb, const __bf16* __restrict__ wb,
    __bf16* __restrict__ qo, __bf16* __restrict__ ko, __bf16* __restrict__ vto)
{
    __shared__ __bf16 As[128][32];
    __shared__ __bf16 Bs[128][32];

    const int tid = threadIdx.x;
    const int l  = tid & 63;
    const int w  = tid >> 6;
    const int wm = w >> 1, wn = w & 1;
    const int lr = l & 15, lg = l >> 4, lk = lg * 8;
    const int m0 = blockIdx.y * 128;
    const int n0 = blockIdx.x * 128;
    const int mat = n0 >> 10;           // 0=q,1=k,2=v
    const int nb  = n0 & 1023;

    const int sr = l >> 2;
    const int sc = (l & 3) * 8;
    const int g0 = w * 2;

    f32x4 acc[4][4] = {};

    for (int d = 0; d < D_DIM; d += 32) {
        __builtin_amdgcn_global_load_lds(
            (const __attribute__((address_space(1))) void*)(xb + (size_t)(m0 + g0 * 16 + sr) * D_DIM + d + sc),
            (__attribute__((address_space(3))) void*)(&As[g0 * 16][0]), 16, 0, 0);
        __builtin_amdgcn_global_load_lds(
            (const __attribute__((address_space(1))) void*)(xb + (size_t)(m0 + (g0 + 1) * 16 + sr) * D_DIM + d + sc),
            (__attribute__((address_space(3))) void*)(&As[(g0 + 1) * 16][0]), 16, 0, 0);
        __builtin_amdgcn_global_load_lds(
            (const __attribute__((address_space(1))) void*)(wb + (size_t)(n0 + g0 * 16 + sr) * D_DIM + d + sc),
            (__attribute__((address_space(3))) void*)(&Bs[g0 * 16][0]), 16, 0, 0);
        __builtin_amdgcn_global_load_lds(
            (const __attribute__((address_space(1))) void*)(wb + (size_t)(n0 + (g0 + 1) * 16 + sr) * D_DIM + d + sc),
            (__attribute__((address_space(3))) void*)(&Bs[(g0 + 1) * 16][0]), 16, 0, 0);
        __syncthreads();

        bf16x8 af[4], bfr[4];
        #pragma unroll
        for (int mi = 0; mi < 4; ++mi)
            af[mi] = *reinterpret_cast<const bf16x8*>(&As[wm * 64 + mi * 16 + lr][lk]);
        #pragma unroll
        for (int ni = 0; ni < 4; ++ni)
            bfr[ni] = *reinterpret_cast<const bf16x8*>(&Bs[wn * 64 + ni * 16 + lr][lk]);
        #pragma unroll
        for (int mi = 0; mi < 4; ++mi) {
            #pragma unroll
            for (int ni = 0; ni < 4; ++ni)
                acc[mi][ni] = __builtin_amdgcn_mfma_f32_16x16x32_bf16(
                    af[mi], bfr[ni], acc[mi][ni], 0, 0, 0);
        }
        __syncthreads();
    }

    const float oscale = (mat == 0) ? QSCALE : 1.0f;
    #pragma unroll
    for (int mi = 0; mi < 4; ++mi) {
        const int mrow = m0 + wm * 64 + mi * 16 + lg * 4;
        const int b = mrow >> 11;
        const int s = mrow & (S_LEN - 1);
        #pragma unroll
        for (int ni = 0; ni < 4; ++ni) {
            const int n = nb + wn * 64 + ni * 16 + lr;
            const int h = n >> 6;
            const int e = n & 63;
            if (mat == 2) {
                bf16x4 pk;
                #pragma unroll
                for (int r = 0; r < 4; ++r) pk[r] = (__bf16)acc[mi][ni][r];
                *reinterpret_cast<bf16x4*>(
                    vto + ((size_t)(b * NHEAD + h) * HDIM + e) * S_LEN + s) = pk;
            } else {
                __bf16* __restrict__ dst = (mat == 0) ? qo : ko;
                #pragma unroll
                for (int r = 0; r < 4; ++r)
                    dst[((size_t)(b * NHEAD + h) * S_LEN + (s + r)) * HDIM + e] =
                        (__bf16)(acc[mi][ni][r] * oscale);
            }
        }
    }
}

// ---------------------------------------------------------------------------
// One KV iteration (64 kv) for a QUAD of 16-row q-tiles (R7-proven body):
// swapped QK^T (lane's q-row = qw+lr), V early-issue, branch-free softmax,
// swapped PV (acc col = own q-row). K direct from global (L2-resident).
// ---------------------------------------------------------------------------
template<bool MASK>
__device__ __attribute__((always_inline)) inline void quad_compute(
    int kv0, int qbase, int lr, int lg, int lk, int swz,
    const __bf16* __restrict__ kp, const __bf16* __restrict__ vp,
    const bf16x8 (&bq0)[4], const bf16x8 (&bq1)[4],
    float (&m_acc)[4], float (&l_acc)[4], f32x4 (&acc)[4][4],
    __bf16* pl_base)
{
    // ---- shared K fragments ----
    bf16x8 ka0[4], ka1[4];
    #pragma unroll
    for (int c = 0; c < 4; ++c) {
        const __bf16* krow = kp + (size_t)(kv0 + c * 16 + lr) * HDIM;
        ka0[c] = *reinterpret_cast<const bf16x8*>(krow + lk);
        ka1[c] = *reinterpret_cast<const bf16x8*>(krow + 32 + lk);
    }
    // ---- V early issue (consumed only at PV) ----
    bf16x8 av[2][4];
    #pragma unroll
    for (int ni = 0; ni < 4; ++ni) {
        const __bf16* vrow = vp + (size_t)(ni * 16 + lr) * S_LEN + kv0;
        av[0][ni] = *reinterpret_cast<const bf16x8*>(vrow + lk);
        av[1][ni] = *reinterpret_cast<const bf16x8*>(vrow + 32 + lk);
    }

    // ---- per-tile QK^T + branch-free online softmax ----
    #pragma unroll
    for (int i = 0; i < 4; ++i) {
        __bf16* pl = pl_base + i * (16 * 64);
        f32x4 s[4];
        __builtin_amdgcn_s_setprio(1);
        #pragma unroll
        for (int c = 0; c < 4; ++c) {
            f32x4 tt = {};
            tt = __builtin_amdgcn_mfma_f32_16x16x32_bf16(ka0[c], bq0[i], tt, 0, 0, 0);
            tt = __builtin_amdgcn_mfma_f32_16x16x32_bf16(ka1[c], bq1[i], tt, 0, 0, 0);
            s[c] = tt;
        }
        __builtin_amdgcn_s_setprio(0);

        if (MASK) {
            const int qrow = qbase + i * 16 + lr;
            #pragma unroll
            for (int c = 0; c < 4; ++c)
                #pragma unroll
                for (int r = 0; r < 4; ++r)
                    if (kv0 + c * 16 + lg * 4 + r > qrow) s[c][r] = -1e30f;
        }

        float a0 = fmaxf(fmaxf(s[0][0], s[0][1]), fmaxf(s[0][2], s[0][3]));
        float a1 = fmaxf(fmaxf(s[1][0], s[1][1]), fmaxf(s[1][2], s[1][3]));
        float a2 = fmaxf(fmaxf(s[2][0], s[2][1]), fmaxf(s[2][2], s[2][3]));
        float a3 = fmaxf(fmaxf(s[3][0], s[3][1]), fmaxf(s[3][2], s[3][3]));
        float mx = fmaxf(fmaxf(a0, a1), fmaxf(a2, a3));
        mx = fmaxf(mx, __shfl_xor(mx, 16));
        mx = fmaxf(mx, __shfl_xor(mx, 32));

        const float mnew = fmaxf(m_acc[i], mx);
        const float sc = exp2f(m_acc[i] - mnew);
        m_acc[i] = mnew;

        float psum = 0.0f;
        #pragma unroll
        for (int c = 0; c < 4; ++c) {
            const float p0 = exp2f(s[c][0] - mnew);
            const float p1 = exp2f(s[c][1] - mnew);
            const float p2 = exp2f(s[c][2] - mnew);
            const float p3 = exp2f(s[c][3] - mnew);
            psum += (p0 + p1) + (p2 + p3);
            uint2 pk;
            pk.x = bf16_bits(p0) | (bf16_bits(p1) << 16);
            pk.y = bf16_bits(p2) | (bf16_bits(p3) << 16);
            *reinterpret_cast<uint2*>(pl + lr * 64 + ((c * 16 + lg * 4) ^ swz)) = pk;
        }
        psum += __shfl_xor(psum, 16);
        psum += __shfl_xor(psum, 32);
        l_acc[i] = l_acc[i] * sc + psum;

        #pragma unroll
        for (int ni = 0; ni < 4; ++ni) acc[i][ni] *= sc;   // per-lane q-row
    }

    // ---- PV (swapped): shared V fragments, acc cols = own q-row ----
    __builtin_amdgcn_s_setprio(1);
    #pragma unroll
    for (int c2 = 0; c2 < 2; ++c2) {
        #pragma unroll
        for (int i = 0; i < 4; ++i) {
            __bf16* pl = pl_base + i * (16 * 64);
            const bf16x8 pa = *reinterpret_cast<const bf16x8*>(
                pl + lr * 64 + ((c2 * 32 + lk) ^ swz));
            #pragma unroll
            for (int ni = 0; ni < 4; ++ni)
                acc[i][ni] = __builtin_amdgcn_mfma_f32_16x16x32_bf16(
                    av[c2][ni], pa, acc[i][ni], 0, 0, 0);
        }
    }
    __builtin_amdgcn_s_setprio(0);
}

// ---------------------------------------------------------------------------
// Causal flash attention, SPLIT-K (codegen-safe): one quad (64 q-rows) per
// 2-wave block; wave w handles kv iterations j == w (mod 2), own (m,l,acc).
// Merge: wave 1 EXPOSES all 4 tiles to LDS (static reg indices, unrolled),
// one barrier, wave 0 MERGES all 4 tiles (static indices) and writes all
// output rows. No runtime-indexed register arrays anywhere (rule #20 --
// R10's dynamic acc[t] demoted acc to scratch: VGPR 84 + 607MB spill writes).
// ---------------------------------------------------------------------------
__global__ __launch_bounds__(128, 4) void attn_kernel(
    const __bf16* __restrict__ q, const __bf16* __restrict__ k,
    const __bf16* __restrict__ vt, float* __restrict__ out)
{
    // compute phase: 2 x 8KB P buffers. merge phase: accbuf [4][16][68] f32
    // (stride 68 = +4 pad: 2-way bank conflicts max) + m/l [4][16] each.
    __shared__ __align__(16) unsigned char smem[4 * 1088 * 4 + 512];

    const int tid = threadIdx.x;
    const int l  = tid & 63;
    const int w  = tid >> 6;             // 0 or 1: kv parity
    const int lr = l & 15;
    const int lg = l >> 4;
    const int lk = lg * 8;
    const int swz = (lr & 7) << 3;

    const int n   = blockIdx.x;
    const int xcd = n & 7;
    const int m   = n >> 3;              // 0..255
    const int qq  = 31 - (m >> 3);       // quad index, longest first
    const int bh  = xcd * 8 + (m & 7);

    const __bf16* __restrict__ kp = k  + (size_t)bh * S_LEN * HDIM;
    const __bf16* __restrict__ vp = vt + (size_t)bh * HDIM * S_LEN;
    const int bq = bh >> 4;
    const int hq = bh & 15;

    const int qbase = qq * 64;

    const __bf16* __restrict__ qp = q + ((size_t)bh * S_LEN + qbase) * HDIM;
    bf16x8 bq0[4], bq1[4];
    #pragma unroll
    for (int i = 0; i < 4; ++i) {
        bq0[i] = *reinterpret_cast<const bf16x8*>(qp + (size_t)(i * 16 + lr) * HDIM + lk);
        bq1[i] = *reinterpret_cast<const bf16x8*>(qp + (size_t)(i * 16 + lr) * HDIM + 32 + lk);
    }

    float m_acc[4], l_acc[4];
    f32x4 acc[4][4] = {};
    #pragma unroll
    for (int i = 0; i < 4; ++i) { m_acc[i] = -1e30f; l_acc[i] = 0.0f; }

    __bf16* pl_base = reinterpret_cast<__bf16*>(smem) + w * 4096;  // 8KB each

    // ---- split-K loop: wave w takes j = w, w+2, ...; diagonal j=qq masked,
    //      handled by the parity-matching wave ----
    #pragma unroll 1
    for (int j = w; j < qq; j += 2)
        quad_compute<false>(j * 64, qbase, lr, lg, lk, swz, kp, vp,
                            bq0, bq1, m_acc, l_acc, acc, pl_base);
    if ((qq & 1) == w)
        quad_compute<true>(qq * 64, qbase, lr, lg, lk, swz, kp, vp,
                           bq0, bq1, m_acc, l_acc, acc, pl_base);

    // ---- merge: wave 1 exposes, wave 0 merges + writes (static indices) ----
    float* accbuf = reinterpret_cast<float*>(smem);               // [4][16][68]
    float* mbuf   = reinterpret_cast<float*>(smem + 4 * 1088 * 4);// [4][16]
    float* lbuf   = mbuf + 64;                                    // [4][16]

    __syncthreads();
    if (w == 1) {
        #pragma unroll
        for (int t = 0; t < 4; ++t) {
            #pragma unroll
            for (int ni = 0; ni < 4; ++ni)
                *reinterpret_cast<f32x4*>(
                    &accbuf[t * 1088 + lr * 68 + ni * 16 + lg * 4]) = acc[t][ni];
            if (lg == 0) {
                mbuf[t * 16 + lr] = m_acc[t];
                lbuf[t * 16 + lr] = l_acc[t];
            }
        }
    }
    __syncthreads();
    if (w == 0) {
        #pragma unroll
        for (int t = 0; t < 4; ++t) {
            const float mo = mbuf[t * 16 + lr];
            const float lo = lbuf[t * 16 + lr];
            const float mn = fmaxf(m_acc[t], mo);
            const float s_own = exp2f(m_acc[t] - mn);
            const float s_oth = exp2f(mo - mn);
            const float liv = 1.0f / (l_acc[t] * s_own + lo * s_oth);
            float* orow = out + (size_t)(bq * S_LEN + qbase + t * 16 + lr) * D_DIM + hq * HDIM;
            #pragma unroll
            for (int ni = 0; ni < 4; ++ni) {
                const f32x4 oth = *reinterpret_cast<const f32x4*>(
                    &accbuf[t * 1088 + lr * 68 + ni * 16 + lg * 4]);
                f32x4 ox;
                #pragma unroll
                for (int r = 0; r < 4; ++r)
                    ox[r] = (acc[t][ni][r] * s_own + oth[r] * s_oth) * liv;
                *reinterpret_cast<f32x4*>(orow + ni * 16 + lg * 4) = ox;
            }
        }
    }
}

extern "C" void kernel_launch(void* const* d_in, const int* in_sizes, int n_in,
                              void* d_out, int out_size, void* d_ws, size_t ws_size,
                              hipStream_t stream)
{
    const float* x  = (const float*)d_in[0];
    const float* Wq = (const float*)d_in[1];
    const float* Wk = (const float*)d_in[2];
    const float* Wv = (const float*)d_in[3];
    float* out = (float*)d_out;

    const size_t x_elems = (size_t)BATCH * S_LEN * D_DIM;
    const size_t w_elems = (size_t)D_DIM * D_DIM;
    __bf16* xb   = (__bf16*)d_out;          // scratch in d_out (overwritten)
    __bf16* wcat = xb + x_elems;

    const size_t per_buf = (size_t)BATCH * NHEAD * S_LEN * HDIM;
    __bf16* qb = (__bf16*)d_ws;
    __bf16* kb = qb + per_buf;
    __bf16* vb = kb + per_buf;

    cvt_kernel<<<(int)(x_elems / 8 / 256), 256, 0, stream>>>(x, xb, (int)(x_elems / 8));
    cvt_kernel<<<(int)(w_elems / 8 / 256), 256, 0, stream>>>(Wq, wcat, (int)(w_elems / 8));
    cvt_kernel<<<(int)(w_elems / 8 / 256), 256, 0, stream>>>(Wk, wcat + w_elems, (int)(w_elems / 8));
    cvt_kernel<<<(int)(w_elems / 8 / 256), 256, 0, stream>>>(Wv, wcat + 2 * w_elems, (int)(w_elems / 8));

    dim3 grid1(3 * D_DIM / 128, (BATCH * S_LEN) / 128);   // (24, 64)
    proj_gemm_kernel<<<grid1, dim3(256), 0, stream>>>(xb, wcat, qb, kb, vb);

    attn_kernel<<<dim3(2048), dim3(128), 0, stream>>>(qb, kb, vb, out);
}

// Round 12
// 185.866 us; speedup vs baseline: 2.3911x; 2.3911x over previous
//
#include <hip/hip_runtime.h>
#include <hip/hip_bf16.h>

#define BATCH 4
#define S_LEN 2048
#define D_DIM 1024
#define NHEAD 16
#define HDIM 64

// Q pre-scale: 1/sqrt(HDIM) * log2(e), so softmax works in exp2 domain.
#define QSCALE 0.18033688011112042f

typedef __attribute__((ext_vector_type(8))) __bf16 bf16x8;
typedef __attribute__((ext_vector_type(4))) __bf16 bf16x4;
typedef __attribute__((ext_vector_type(4))) float f32x4;

static __device__ inline unsigned int bf16_bits(float f) {
    __bf16 h = (__bf16)f;
    return (unsigned int)__builtin_bit_cast(unsigned short, h);
}

// ---------------------------------------------------------------------------
// fp32 -> bf16 bulk convert, 8 elems/thread, 16B stores.
// ---------------------------------------------------------------------------
__global__ __launch_bounds__(256) void cvt_kernel(
    const float* __restrict__ src, __bf16* __restrict__ dst, int n8)
{
    int i = blockIdx.x * 256 + threadIdx.x;
    if (i >= n8) return;
    const f32x4* p = reinterpret_cast<const f32x4*>(src + (size_t)i * 8);
    f32x4 a = p[0], b = p[1];
    bf16x8 r;
    r[0] = (__bf16)a[0]; r[1] = (__bf16)a[1]; r[2] = (__bf16)a[2]; r[3] = (__bf16)a[3];
    r[4] = (__bf16)b[0]; r[5] = (__bf16)b[1]; r[6] = (__bf16)b[2]; r[7] = (__bf16)b[3];
    *reinterpret_cast<bf16x8*>(dst + (size_t)i * 8) = r;
}

// ---------------------------------------------------------------------------
// Projection GEMM (m97-style): C[m][n] = sum_d xb[m][d] * wb[n][d]
// q output is pre-scaled by QSCALE. q,k -> [bh][s][e]; v -> [bh][e][s].
// ---------------------------------------------------------------------------
__global__ __launch_bounds__(256) void proj_gemm_kernel(
    const __bf16* __restrict__ xb, const __bf16* __restrict__ wb,
    __bf16* __restrict__ qo, __bf16* __restrict__ ko, __bf16* __restrict__ vto)
{
    __shared__ __bf16 As[128][32];
    __shared__ __bf16 Bs[128][32];

    const int tid = threadIdx.x;
    const int l  = tid & 63;
    const int w  = tid >> 6;
    const int wm = w >> 1, wn = w & 1;
    const int lr = l & 15, lg = l >> 4, lk = lg * 8;
    const int m0 = blockIdx.y * 128;
    const int n0 = blockIdx.x * 128;
    const int mat = n0 >> 10;           // 0=q,1=k,2=v
    const int nb  = n0 & 1023;

    const int sr = l >> 2;
    const int sc = (l & 3) * 8;
    const int g0 = w * 2;

    f32x4 acc[4][4] = {};

    for (int d = 0; d < D_DIM; d += 32) {
        __builtin_amdgcn_global_load_lds(
            (const __attribute__((address_space(1))) void*)(xb + (size_t)(m0 + g0 * 16 + sr) * D_DIM + d + sc),
            (__attribute__((address_space(3))) void*)(&As[g0 * 16][0]), 16, 0, 0);
        __builtin_amdgcn_global_load_lds(
            (const __attribute__((address_space(1))) void*)(xb + (size_t)(m0 + (g0 + 1) * 16 + sr) * D_DIM + d + sc),
            (__attribute__((address_space(3))) void*)(&As[(g0 + 1) * 16][0]), 16, 0, 0);
        __builtin_amdgcn_global_load_lds(
            (const __attribute__((address_space(1))) void*)(wb + (size_t)(n0 + g0 * 16 + sr) * D_DIM + d + sc),
            (__attribute__((address_space(3))) void*)(&Bs[g0 * 16][0]), 16, 0, 0);
        __builtin_amdgcn_global_load_lds(
            (const __attribute__((address_space(1))) void*)(wb + (size_t)(n0 + (g0 + 1) * 16 + sr) * D_DIM + d + sc),
            (__attribute__((address_space(3))) void*)(&Bs[(g0 + 1) * 16][0]), 16, 0, 0);
        __syncthreads();

        bf16x8 af[4], bfr[4];
        #pragma unroll
        for (int mi = 0; mi < 4; ++mi)
            af[mi] = *reinterpret_cast<const bf16x8*>(&As[wm * 64 + mi * 16 + lr][lk]);
        #pragma unroll
        for (int ni = 0; ni < 4; ++ni)
            bfr[ni] = *reinterpret_cast<const bf16x8*>(&Bs[wn * 64 + ni * 16 + lr][lk]);
        #pragma unroll
        for (int mi = 0; mi < 4; ++mi) {
            #pragma unroll
            for (int ni = 0; ni < 4; ++ni)
                acc[mi][ni] = __builtin_amdgcn_mfma_f32_16x16x32_bf16(
                    af[mi], bfr[ni], acc[mi][ni], 0, 0, 0);
        }
        __syncthreads();
    }

    const float oscale = (mat == 0) ? QSCALE : 1.0f;
    #pragma unroll
    for (int mi = 0; mi < 4; ++mi) {
        const int mrow = m0 + wm * 64 + mi * 16 + lg * 4;
        const int b = mrow >> 11;
        const int s = mrow & (S_LEN - 1);
        #pragma unroll
        for (int ni = 0; ni < 4; ++ni) {
            const int n = nb + wn * 64 + ni * 16 + lr;
            const int h = n >> 6;
            const int e = n & 63;
            if (mat == 2) {
                bf16x4 pk;
                #pragma unroll
                for (int r = 0; r < 4; ++r) pk[r] = (__bf16)acc[mi][ni][r];
                *reinterpret_cast<bf16x4*>(
                    vto + ((size_t)(b * NHEAD + h) * HDIM + e) * S_LEN + s) = pk;
            } else {
                __bf16* __restrict__ dst = (mat == 0) ? qo : ko;
                #pragma unroll
                for (int r = 0; r < 4; ++r)
                    dst[((size_t)(b * NHEAD + h) * S_LEN + (s + r)) * HDIM + e] =
                        (__bf16)(acc[mi][ni][r] * oscale);
            }
        }
    }
}

// ---------------------------------------------------------------------------
// One KV iteration (64 kv) for a QUAD of 16-row q-tiles (R7-proven body)
// with latency-reduced softmax:
//   - per-lane deferred l: l_lane accumulates own-16 exp2 sums; the xor16/32
//     reduction happens ONCE in the epilogue (valid: m is row-uniform).
//   - defer-max (T13): the cross-lane max reduce + acc rescale run only when
//     a lane's local max grew past m_acc + 8 (P bounded by 2^8, fp32 absorbs).
//     First iteration triggers it (m = -1e30), establishing a proper row max.
// Fast path has ZERO cross-lane ops.
// ---------------------------------------------------------------------------
template<bool MASK>
__device__ __attribute__((always_inline)) inline void quad_compute(
    int kv0, int qbase, int lr, int lg, int lk, int swz,
    const __bf16* __restrict__ kp, const __bf16* __restrict__ vp,
    const bf16x8 (&bq0)[4], const bf16x8 (&bq1)[4],
    float (&m_acc)[4], float (&l_lane)[4], f32x4 (&acc)[4][4],
    __bf16* pl_base)
{
    // ---- shared K fragments ----
    bf16x8 ka0[4], ka1[4];
    #pragma unroll
    for (int c = 0; c < 4; ++c) {
        const __bf16* krow = kp + (size_t)(kv0 + c * 16 + lr) * HDIM;
        ka0[c] = *reinterpret_cast<const bf16x8*>(krow + lk);
        ka1[c] = *reinterpret_cast<const bf16x8*>(krow + 32 + lk);
    }
    // ---- V early issue (consumed only at PV) ----
    bf16x8 av[2][4];
    #pragma unroll
    for (int ni = 0; ni < 4; ++ni) {
        const __bf16* vrow = vp + (size_t)(ni * 16 + lr) * S_LEN + kv0;
        av[0][ni] = *reinterpret_cast<const bf16x8*>(vrow + lk);
        av[1][ni] = *reinterpret_cast<const bf16x8*>(vrow + 32 + lk);
    }

    // ---- per-tile QK^T + deferred-max online softmax ----
    #pragma unroll
    for (int i = 0; i < 4; ++i) {
        __bf16* pl = pl_base + i * (16 * 64);
        f32x4 s[4];
        __builtin_amdgcn_s_setprio(1);
        #pragma unroll
        for (int c = 0; c < 4; ++c) {
            f32x4 tt = {};
            tt = __builtin_amdgcn_mfma_f32_16x16x32_bf16(ka0[c], bq0[i], tt, 0, 0, 0);
            tt = __builtin_amdgcn_mfma_f32_16x16x32_bf16(ka1[c], bq1[i], tt, 0, 0, 0);
            s[c] = tt;
        }
        __builtin_amdgcn_s_setprio(0);

        if (MASK) {
            const int qrow = qbase + i * 16 + lr;
            #pragma unroll
            for (int c = 0; c < 4; ++c)
                #pragma unroll
                for (int r = 0; r < 4; ++r)
                    if (kv0 + c * 16 + lg * 4 + r > qrow) s[c][r] = -1e30f;
        }

        // lane-local max over own 16 scores
        float a0 = fmaxf(fmaxf(s[0][0], s[0][1]), fmaxf(s[0][2], s[0][3]));
        float a1 = fmaxf(fmaxf(s[1][0], s[1][1]), fmaxf(s[1][2], s[1][3]));
        float a2 = fmaxf(fmaxf(s[2][0], s[2][1]), fmaxf(s[2][2], s[2][3]));
        float a3 = fmaxf(fmaxf(s[3][0], s[3][1]), fmaxf(s[3][2], s[3][3]));
        float mx = fmaxf(fmaxf(a0, a1), fmaxf(a2, a3));

        // defer-max: cross-lane reduce + rescale only on significant growth
        if (!__all(mx - m_acc[i] <= 8.0f)) {
            mx = fmaxf(mx, __shfl_xor(mx, 16));
            mx = fmaxf(mx, __shfl_xor(mx, 32));
            const float mnew = fmaxf(m_acc[i], mx);
            const float sc = exp2f(m_acc[i] - mnew);
            l_lane[i] *= sc;
            #pragma unroll
            for (int ni = 0; ni < 4; ++ni) acc[i][ni] *= sc;  // per-lane q-row
            m_acc[i] = mnew;
        }

        // P = exp2(s - m); per-lane l partial only (no cross-lane here)
        const float mi_ = m_acc[i];
        float psum = 0.0f;
        #pragma unroll
        for (int c = 0; c < 4; ++c) {
            const float p0 = exp2f(s[c][0] - mi_);
            const float p1 = exp2f(s[c][1] - mi_);
            const float p2 = exp2f(s[c][2] - mi_);
            const float p3 = exp2f(s[c][3] - mi_);
            psum += (p0 + p1) + (p2 + p3);
            uint2 pk;
            pk.x = bf16_bits(p0) | (bf16_bits(p1) << 16);
            pk.y = bf16_bits(p2) | (bf16_bits(p3) << 16);
            *reinterpret_cast<uint2*>(pl + lr * 64 + ((c * 16 + lg * 4) ^ swz)) = pk;
        }
        l_lane[i] += psum;
    }

    // ---- PV (swapped): shared V fragments, acc cols = own q-row ----
    __builtin_amdgcn_s_setprio(1);
    #pragma unroll
    for (int c2 = 0; c2 < 2; ++c2) {
        #pragma unroll
        for (int i = 0; i < 4; ++i) {
            __bf16* pl = pl_base + i * (16 * 64);
            const bf16x8 pa = *reinterpret_cast<const bf16x8*>(
                pl + lr * 64 + ((c2 * 32 + lk) ^ swz));
            #pragma unroll
            for (int ni = 0; ni < 4; ++ni)
                acc[i][ni] = __builtin_amdgcn_mfma_f32_16x16x32_bf16(
                    av[c2][ni], pa, acc[i][ni], 0, 0, 0);
        }
    }
    __builtin_amdgcn_s_setprio(0);
}

// ---------------------------------------------------------------------------
// Causal flash attention: QUAD of 16-row q-tiles (64 rows) per 1-wave block
// (R7 structure, 124us) + zero-shfl fast-path softmax (defer-max + deferred
// per-lane l). Grid 2048 waves, longest-first, heads pinned to XCD.
// launch_bounds(64,2): 256-reg budget -- the unified VGPR+AGPR footprint is
// ~180; tighter bounds (R10/R11) forced catastrophic spill.
// ---------------------------------------------------------------------------
__global__ __launch_bounds__(64, 2) void attn_kernel(
    const __bf16* __restrict__ q, const __bf16* __restrict__ k,
    const __bf16* __restrict__ vt, float* __restrict__ out)
{
    __shared__ __bf16 plds[4][16][64];

    const int l  = threadIdx.x;
    const int lr = l & 15;
    const int lg = l >> 4;
    const int lk = lg * 8;
    const int swz = (lr & 7) << 3;

    const int n   = blockIdx.x;
    const int xcd = n & 7;
    const int m   = n >> 3;              // 0..255
    const int qq  = 31 - (m >> 3);       // quad index, longest first
    const int bh  = xcd * 8 + (m & 7);

    const __bf16* __restrict__ kp = k  + (size_t)bh * S_LEN * HDIM;
    const __bf16* __restrict__ vp = vt + (size_t)bh * HDIM * S_LEN;
    const int bq = bh >> 4;
    const int hq = bh & 15;

    const int qbase = qq * 64;
    const int iters = qq + 1;

    const __bf16* __restrict__ qp = q + ((size_t)bh * S_LEN + qbase) * HDIM;
    bf16x8 bq0[4], bq1[4];
    #pragma unroll
    for (int i = 0; i < 4; ++i) {
        bq0[i] = *reinterpret_cast<const bf16x8*>(qp + (size_t)(i * 16 + lr) * HDIM + lk);
        bq1[i] = *reinterpret_cast<const bf16x8*>(qp + (size_t)(i * 16 + lr) * HDIM + 32 + lk);
    }

    float m_acc[4], l_lane[4];
    f32x4 acc[4][4] = {};
    #pragma unroll
    for (int i = 0; i < 4; ++i) { m_acc[i] = -1e30f; l_lane[i] = 0.0f; }

    __bf16* pl_base = &plds[0][0][0];

    #pragma unroll 1
    for (int j = 0; j < iters - 1; ++j)
        quad_compute<false>(j * 64, qbase, lr, lg, lk, swz, kp, vp,
                            bq0, bq1, m_acc, l_lane, acc, pl_base);
    quad_compute<true>((iters - 1) * 64, qbase, lr, lg, lk, swz, kp, vp,
                       bq0, bq1, m_acc, l_lane, acc, pl_base);

    // ---- epilogue: reduce l once; lane's q-row = qbase + 16i + lr ----
    #pragma unroll
    for (int i = 0; i < 4; ++i) {
        float lt = l_lane[i];
        lt += __shfl_xor(lt, 16);
        lt += __shfl_xor(lt, 32);
        const float liv = 1.0f / lt;
        float* orow = out + (size_t)(bq * S_LEN + qbase + i * 16 + lr) * D_DIM + hq * HDIM;
        #pragma unroll
        for (int ni = 0; ni < 4; ++ni) {
            f32x4 ox;
            #pragma unroll
            for (int r = 0; r < 4; ++r) ox[r] = acc[i][ni][r] * liv;
            *reinterpret_cast<f32x4*>(orow + ni * 16 + lg * 4) = ox;
        }
    }
}

extern "C" void kernel_launch(void* const* d_in, const int* in_sizes, int n_in,
                              void* d_out, int out_size, void* d_ws, size_t ws_size,
                              hipStream_t stream)
{
    const float* x  = (const float*)d_in[0];
    const float* Wq = (const float*)d_in[1];
    const float* Wk = (const float*)d_in[2];
    const float* Wv = (const float*)d_in[3];
    float* out = (float*)d_out;

    const size_t x_elems = (size_t)BATCH * S_LEN * D_DIM;
    const size_t w_elems = (size_t)D_DIM * D_DIM;
    __bf16* xb   = (__bf16*)d_out;          // scratch in d_out (overwritten)
    __bf16* wcat = xb + x_elems;

    const size_t per_buf = (size_t)BATCH * NHEAD * S_LEN * HDIM;
    __bf16* qb = (__bf16*)d_ws;
    __bf16* kb = qb + per_buf;
    __bf16* vb = kb + per_buf;

    cvt_kernel<<<(int)(x_elems / 8 / 256), 256, 0, stream>>>(x, xb, (int)(x_elems / 8));
    cvt_kernel<<<(int)(w_elems / 8 / 256), 256, 0, stream>>>(Wq, wcat, (int)(w_elems / 8));
    cvt_kernel<<<(int)(w_elems / 8 / 256), 256, 0, stream>>>(Wk, wcat + w_elems, (int)(w_elems / 8));
    cvt_kernel<<<(int)(w_elems / 8 / 256), 256, 0, stream>>>(Wv, wcat + 2 * w_elems, (int)(w_elems / 8));

    dim3 grid1(3 * D_DIM / 128, (BATCH * S_LEN) / 128);   // (24, 64)
    proj_gemm_kernel<<<grid1, dim3(256), 0, stream>>>(xb, wcat, qb, kb, vb);

    attn_kernel<<<dim3(2048), dim3(64), 0, stream>>>(qb, kb, vb, out);
}

// Round 13
// 184.318 us; speedup vs baseline: 2.4112x; 1.0084x over previous
//
#include <hip/hip_runtime.h>
#include <hip/hip_bf16.h>

#define BATCH 4
#define S_LEN 2048
#define D_DIM 1024
#define NHEAD 16
#define HDIM 64

// Q pre-scale: 1/sqrt(HDIM) * log2(e), so softmax works in exp2 domain.
#define QSCALE 0.18033688011112042f

typedef __attribute__((ext_vector_type(8))) __bf16 bf16x8;
typedef __attribute__((ext_vector_type(4))) __bf16 bf16x4;
typedef __attribute__((ext_vector_type(4))) float f32x4;

static __device__ inline unsigned int bf16_bits(float f) {
    __bf16 h = (__bf16)f;
    return (unsigned int)__builtin_bit_cast(unsigned short, h);
}

// ---------------------------------------------------------------------------
// fp32 -> bf16 bulk convert, 8 elems/thread, 16B stores.
// ---------------------------------------------------------------------------
__global__ __launch_bounds__(256) void cvt_kernel(
    const float* __restrict__ src, __bf16* __restrict__ dst, int n8)
{
    int i = blockIdx.x * 256 + threadIdx.x;
    if (i >= n8) return;
    const f32x4* p = reinterpret_cast<const f32x4*>(src + (size_t)i * 8);
    f32x4 a = p[0], b = p[1];
    bf16x8 r;
    r[0] = (__bf16)a[0]; r[1] = (__bf16)a[1]; r[2] = (__bf16)a[2]; r[3] = (__bf16)a[3];
    r[4] = (__bf16)b[0]; r[5] = (__bf16)b[1]; r[6] = (__bf16)b[2]; r[7] = (__bf16)b[3];
    *reinterpret_cast<bf16x8*>(dst + (size_t)i * 8) = r;
}

// ---------------------------------------------------------------------------
// Projection GEMM (m97-style): C[m][n] = sum_d xb[m][d] * wb[n][d]
// q output is pre-scaled by QSCALE. q,k -> [bh][s][e]; v -> [bh][e][s].
// ---------------------------------------------------------------------------
__global__ __launch_bounds__(256) void proj_gemm_kernel(
    const __bf16* __restrict__ xb, const __bf16* __restrict__ wb,
    __bf16* __restrict__ qo, __bf16* __restrict__ ko, __bf16* __restrict__ vto)
{
    __shared__ __bf16 As[128][32];
    __shared__ __bf16 Bs[128][32];

    const int tid = threadIdx.x;
    const int l  = tid & 63;
    const int w  = tid >> 6;
    const int wm = w >> 1, wn = w & 1;
    const int lr = l & 15, lg = l >> 4, lk = lg * 8;
    const int m0 = blockIdx.y * 128;
    const int n0 = blockIdx.x * 128;
    const int mat = n0 >> 10;           // 0=q,1=k,2=v
    const int nb  = n0 & 1023;

    const int sr = l >> 2;
    const int sc = (l & 3) * 8;
    const int g0 = w * 2;

    f32x4 acc[4][4] = {};

    for (int d = 0; d < D_DIM; d += 32) {
        __builtin_amdgcn_global_load_lds(
            (const __attribute__((address_space(1))) void*)(xb + (size_t)(m0 + g0 * 16 + sr) * D_DIM + d + sc),
            (__attribute__((address_space(3))) void*)(&As[g0 * 16][0]), 16, 0, 0);
        __builtin_amdgcn_global_load_lds(
            (const __attribute__((address_space(1))) void*)(xb + (size_t)(m0 + (g0 + 1) * 16 + sr) * D_DIM + d + sc),
            (__attribute__((address_space(3))) void*)(&As[(g0 + 1) * 16][0]), 16, 0, 0);
        __builtin_amdgcn_global_load_lds(
            (const __attribute__((address_space(1))) void*)(wb + (size_t)(n0 + g0 * 16 + sr) * D_DIM + d + sc),
            (__attribute__((address_space(3))) void*)(&Bs[g0 * 16][0]), 16, 0, 0);
        __builtin_amdgcn_global_load_lds(
            (const __attribute__((address_space(1))) void*)(wb + (size_t)(n0 + (g0 + 1) * 16 + sr) * D_DIM + d + sc),
            (__attribute__((address_space(3))) void*)(&Bs[(g0 + 1) * 16][0]), 16, 0, 0);
        __syncthreads();

        bf16x8 af[4], bfr[4];
        #pragma unroll
        for (int mi = 0; mi < 4; ++mi)
            af[mi] = *reinterpret_cast<const bf16x8*>(&As[wm * 64 + mi * 16 + lr][lk]);
        #pragma unroll
        for (int ni = 0; ni < 4; ++ni)
            bfr[ni] = *reinterpret_cast<const bf16x8*>(&Bs[wn * 64 + ni * 16 + lr][lk]);
        #pragma unroll
        for (int mi = 0; mi < 4; ++mi) {
            #pragma unroll
            for (int ni = 0; ni < 4; ++ni)
                acc[mi][ni] = __builtin_amdgcn_mfma_f32_16x16x32_bf16(
                    af[mi], bfr[ni], acc[mi][ni], 0, 0, 0);
        }
        __syncthreads();
    }

    const float oscale = (mat == 0) ? QSCALE : 1.0f;
    #pragma unroll
    for (int mi = 0; mi < 4; ++mi) {
        const int mrow = m0 + wm * 64 + mi * 16 + lg * 4;
        const int b = mrow >> 11;
        const int s = mrow & (S_LEN - 1);
        #pragma unroll
        for (int ni = 0; ni < 4; ++ni) {
            const int n = nb + wn * 64 + ni * 16 + lr;
            const int h = n >> 6;
            const int e = n & 63;
            if (mat == 2) {
                bf16x4 pk;
                #pragma unroll
                for (int r = 0; r < 4; ++r) pk[r] = (__bf16)acc[mi][ni][r];
                *reinterpret_cast<bf16x4*>(
                    vto + ((size_t)(b * NHEAD + h) * HDIM + e) * S_LEN + s) = pk;
            } else {
                __bf16* __restrict__ dst = (mat == 0) ? qo : ko;
                #pragma unroll
                for (int r = 0; r < 4; ++r)
                    dst[((size_t)(b * NHEAD + h) * S_LEN + (s + r)) * HDIM + e] =
                        (__bf16)(acc[mi][ni][r] * oscale);
            }
        }
    }
}

// ---------------------------------------------------------------------------
// Named K fragment set for register double-buffering (rule #20: no runtime
// indexing -- parity handled by wave-uniform branch on alternating names).
// ---------------------------------------------------------------------------
struct KFrag { bf16x8 a0[4]; bf16x8 a1[4]; };   // 32 VGPR

__device__ __attribute__((always_inline)) inline void load_k(
    KFrag& kf, const __bf16* __restrict__ kp, int kv0, int lr, int lk)
{
    #pragma unroll
    for (int c = 0; c < 4; ++c) {
        const __bf16* krow = kp + (size_t)(kv0 + c * 16 + lr) * HDIM;
        kf.a0[c] = *reinterpret_cast<const bf16x8*>(krow + lk);
        kf.a1[c] = *reinterpret_cast<const bf16x8*>(krow + 32 + lk);
    }
}

// ---------------------------------------------------------------------------
// One KV iteration (64 kv) for a QUAD of 16-row q-tiles (R12-proven body):
// defer-max + per-lane deferred l (zero cross-lane ops on fast path),
// swapped QK^T / swapped PV, V early-issue. K supplied in registers.
// ---------------------------------------------------------------------------
template<bool MASK>
__device__ __attribute__((always_inline)) inline void quad_compute(
    int kv0, int qbase, int lr, int lg, int lk, int swz,
    const __bf16* __restrict__ vp, const KFrag& kf,
    const bf16x8 (&bq0)[4], const bf16x8 (&bq1)[4],
    float (&m_acc)[4], float (&l_lane)[4], f32x4 (&acc)[4][4],
    __bf16* pl_base)
{
    // ---- V early issue (consumed only at PV) ----
    bf16x8 av[2][4];
    #pragma unroll
    for (int ni = 0; ni < 4; ++ni) {
        const __bf16* vrow = vp + (size_t)(ni * 16 + lr) * S_LEN + kv0;
        av[0][ni] = *reinterpret_cast<const bf16x8*>(vrow + lk);
        av[1][ni] = *reinterpret_cast<const bf16x8*>(vrow + 32 + lk);
    }

    // ---- per-tile QK^T + deferred-max online softmax ----
    #pragma unroll
    for (int i = 0; i < 4; ++i) {
        __bf16* pl = pl_base + i * (16 * 64);
        f32x4 s[4];
        __builtin_amdgcn_s_setprio(1);
        #pragma unroll
        for (int c = 0; c < 4; ++c) {
            f32x4 tt = {};
            tt = __builtin_amdgcn_mfma_f32_16x16x32_bf16(kf.a0[c], bq0[i], tt, 0, 0, 0);
            tt = __builtin_amdgcn_mfma_f32_16x16x32_bf16(kf.a1[c], bq1[i], tt, 0, 0, 0);
            s[c] = tt;
        }
        __builtin_amdgcn_s_setprio(0);

        if (MASK) {
            const int qrow = qbase + i * 16 + lr;
            #pragma unroll
            for (int c = 0; c < 4; ++c)
                #pragma unroll
                for (int r = 0; r < 4; ++r)
                    if (kv0 + c * 16 + lg * 4 + r > qrow) s[c][r] = -1e30f;
        }

        // lane-local max over own 16 scores
        float a0 = fmaxf(fmaxf(s[0][0], s[0][1]), fmaxf(s[0][2], s[0][3]));
        float a1 = fmaxf(fmaxf(s[1][0], s[1][1]), fmaxf(s[1][2], s[1][3]));
        float a2 = fmaxf(fmaxf(s[2][0], s[2][1]), fmaxf(s[2][2], s[2][3]));
        float a3 = fmaxf(fmaxf(s[3][0], s[3][1]), fmaxf(s[3][2], s[3][3]));
        float mx = fmaxf(fmaxf(a0, a1), fmaxf(a2, a3));

        // defer-max: cross-lane reduce + rescale only on significant growth
        if (!__all(mx - m_acc[i] <= 8.0f)) {
            mx = fmaxf(mx, __shfl_xor(mx, 16));
            mx = fmaxf(mx, __shfl_xor(mx, 32));
            const float mnew = fmaxf(m_acc[i], mx);
            const float sc = exp2f(m_acc[i] - mnew);
            l_lane[i] *= sc;
            #pragma unroll
            for (int ni = 0; ni < 4; ++ni) acc[i][ni] *= sc;  // per-lane q-row
            m_acc[i] = mnew;
        }

        // P = exp2(s - m); per-lane l partial only (no cross-lane here)
        const float mi_ = m_acc[i];
        float psum = 0.0f;
        #pragma unroll
        for (int c = 0; c < 4; ++c) {
            const float p0 = exp2f(s[c][0] - mi_);
            const float p1 = exp2f(s[c][1] - mi_);
            const float p2 = exp2f(s[c][2] - mi_);
            const float p3 = exp2f(s[c][3] - mi_);
            psum += (p0 + p1) + (p2 + p3);
            uint2 pk;
            pk.x = bf16_bits(p0) | (bf16_bits(p1) << 16);
            pk.y = bf16_bits(p2) | (bf16_bits(p3) << 16);
            *reinterpret_cast<uint2*>(pl + lr * 64 + ((c * 16 + lg * 4) ^ swz)) = pk;
        }
        l_lane[i] += psum;
    }

    // ---- PV (swapped): shared V fragments, acc cols = own q-row ----
    __builtin_amdgcn_s_setprio(1);
    #pragma unroll
    for (int c2 = 0; c2 < 2; ++c2) {
        #pragma unroll
        for (int i = 0; i < 4; ++i) {
            __bf16* pl = pl_base + i * (16 * 64);
            const bf16x8 pa = *reinterpret_cast<const bf16x8*>(
                pl + lr * 64 + ((c2 * 32 + lk) ^ swz));
            #pragma unroll
            for (int ni = 0; ni < 4; ++ni)
                acc[i][ni] = __builtin_amdgcn_mfma_f32_16x16x32_bf16(
                    av[c2][ni], pa, acc[i][ni], 0, 0, 0);
        }
    }
    __builtin_amdgcn_s_setprio(0);
}

// ---------------------------------------------------------------------------
// Causal flash attention, UNIFORM-MAKESPAN: each 1-wave block sequentially
// processes quads (tp, 31-tp) -> every block is exactly 33 KV-iterations
// (R12's tail: the 32-iter task ran nearly alone; makespan = 32 x solo-wall).
// 1024 blocks = 4/CU, all resident, zero drain. Occupancy is grid-limited,
// so registers are free: K register double-buffer (R8 idea, now spill-safe
// under launch_bounds(64,1) = 512-reg budget) hides K L2 latency at the
// 1-wave/SIMD concurrency this grid runs at.
// ---------------------------------------------------------------------------
__global__ __launch_bounds__(64, 1) void attn_kernel(
    const __bf16* __restrict__ q, const __bf16* __restrict__ k,
    const __bf16* __restrict__ vt, float* __restrict__ out)
{
    __shared__ __bf16 plds[4][16][64];

    const int l  = threadIdx.x;
    const int lr = l & 15;
    const int lg = l >> 4;
    const int lk = lg * 8;
    const int swz = (lr & 7) << 3;

    const int n   = blockIdx.x;          // 0..1023
    const int xcd = n & 7;
    const int m   = n >> 3;              // 0..127
    const int tp  = m >> 3;              // 0..15: pair (tp, 31-tp)
    const int bh  = xcd * 8 + (m & 7);

    const __bf16* __restrict__ kp = k  + (size_t)bh * S_LEN * HDIM;
    const __bf16* __restrict__ vp = vt + (size_t)bh * HDIM * S_LEN;
    const int bq = bh >> 4;
    const int hq = bh & 15;

    __bf16* pl_base = &plds[0][0][0];

    #pragma unroll 1
    for (int ph = 0; ph < 2; ++ph) {
        const int qq    = ph ? (31 - tp) : tp;
        const int qbase = qq * 64;
        const int iters = qq + 1;

        // Q fragments for this quad (B-layout: col = lr = q row, k = e)
        const __bf16* __restrict__ qp = q + ((size_t)bh * S_LEN + qbase) * HDIM;
        bf16x8 bq0[4], bq1[4];
        #pragma unroll
        for (int i = 0; i < 4; ++i) {
            bq0[i] = *reinterpret_cast<const bf16x8*>(qp + (size_t)(i * 16 + lr) * HDIM + lk);
            bq1[i] = *reinterpret_cast<const bf16x8*>(qp + (size_t)(i * 16 + lr) * HDIM + 32 + lk);
        }

        float m_acc[4], l_lane[4];
        f32x4 acc[4][4] = {};
        #pragma unroll
        for (int i = 0; i < 4; ++i) { m_acc[i] = -1e30f; l_lane[i] = 0.0f; }

        KFrag kA, kB;
        load_k(kA, kp, 0, lr, lk);
        bool useA = true;

        #pragma unroll 1
        for (int j = 0; j < iters - 1; ++j) {
            if (useA) {
                load_k(kB, kp, (j + 1) * 64, lr, lk);   // prefetch next
                quad_compute<false>(j * 64, qbase, lr, lg, lk, swz, vp, kA,
                                    bq0, bq1, m_acc, l_lane, acc, pl_base);
            } else {
                load_k(kA, kp, (j + 1) * 64, lr, lk);
                quad_compute<false>(j * 64, qbase, lr, lg, lk, swz, vp, kB,
                                    bq0, bq1, m_acc, l_lane, acc, pl_base);
            }
            useA = !useA;
        }
        if (useA)
            quad_compute<true>((iters - 1) * 64, qbase, lr, lg, lk, swz, vp, kA,
                               bq0, bq1, m_acc, l_lane, acc, pl_base);
        else
            quad_compute<true>((iters - 1) * 64, qbase, lr, lg, lk, swz, vp, kB,
                               bq0, bq1, m_acc, l_lane, acc, pl_base);

        // ---- epilogue: reduce l once; lane's q-row = qbase + 16i + lr ----
        #pragma unroll
        for (int i = 0; i < 4; ++i) {
            float lt = l_lane[i];
            lt += __shfl_xor(lt, 16);
            lt += __shfl_xor(lt, 32);
            const float liv = 1.0f / lt;
            float* orow = out + (size_t)(bq * S_LEN + qbase + i * 16 + lr) * D_DIM + hq * HDIM;
            #pragma unroll
            for (int ni = 0; ni < 4; ++ni) {
                f32x4 ox;
                #pragma unroll
                for (int r = 0; r < 4; ++r) ox[r] = acc[i][ni][r] * liv;
                *reinterpret_cast<f32x4*>(orow + ni * 16 + lg * 4) = ox;
            }
        }
    }
}

extern "C" void kernel_launch(void* const* d_in, const int* in_sizes, int n_in,
                              void* d_out, int out_size, void* d_ws, size_t ws_size,
                              hipStream_t stream)
{
    const float* x  = (const float*)d_in[0];
    const float* Wq = (const float*)d_in[1];
    const float* Wk = (const float*)d_in[2];
    const float* Wv = (const float*)d_in[3];
    float* out = (float*)d_out;

    const size_t x_elems = (size_t)BATCH * S_LEN * D_DIM;
    const size_t w_elems = (size_t)D_DIM * D_DIM;
    __bf16* xb   = (__bf16*)d_out;          // scratch in d_out (overwritten)
    __bf16* wcat = xb + x_elems;

    const size_t per_buf = (size_t)BATCH * NHEAD * S_LEN * HDIM;
    __bf16* qb = (__bf16*)d_ws;
    __bf16* kb = qb + per_buf;
    __bf16* vb = kb + per_buf;

    cvt_kernel<<<(int)(x_elems / 8 / 256), 256, 0, stream>>>(x, xb, (int)(x_elems / 8));
    cvt_kernel<<<(int)(w_elems / 8 / 256), 256, 0, stream>>>(Wq, wcat, (int)(w_elems / 8));
    cvt_kernel<<<(int)(w_elems / 8 / 256), 256, 0, stream>>>(Wk, wcat + w_elems, (int)(w_elems / 8));
    cvt_kernel<<<(int)(w_elems / 8 / 256), 256, 0, stream>>>(Wv, wcat + 2 * w_elems, (int)(w_elems / 8));

    dim3 grid1(3 * D_DIM / 128, (BATCH * S_LEN) / 128);   // (24, 64)
    proj_gemm_kernel<<<grid1, dim3(256), 0, stream>>>(xb, wcat, qb, kb, vb);

    attn_kernel<<<dim3(1024), dim3(64), 0, stream>>>(qb, kb, vb, out);
}